// Round 8
// baseline (157.522 us; speedup 1.0000x reference)
//
#include <hip/hip_runtime.h>

// Model_65678639890859 — round 8: deeper prefetch, one residency round.
//
// History: r6 pinned the LSTM weights in VGPRs (compiler had sunk ~34 weight
// loads into the 64-step serial loop — the hidden ~25us). r7 capped live
// chunks at 2 to kill spills under __launch_bounds__(256,4). Kernel now ~31us
// vs ~18-20us ideal.
//
// r8: __launch_bounds__(256,3) lifts the VGPR cap to ~168:
//   - waves 1-3 prefetch THREE chunks (144 regs, no spill) => ~60MB in flight
//     machine-wide during the LSTM (~9us of drain, covers the LSTM fully).
//   - grid = 768 blocks = exactly 3/CU: ONE residency round, no second-round
//     redundant LSTMs. 5 static chunks + grid-stride remainder.
//   - post-barrier: up to 3 live chunks => loads run 2 chunks ahead.
//
// All tensors float32. LSTM: V=6 rows x U=4 units, rows independent; lane =
// (j,u) on wave 0, cross-lane via DPP quad_perm (rows are aligned quads).
// vels = 2*o0 + o1 + ... + o62 (o63 computed, discarded) — exact reference
// accumulation semantics.

#define V 6
#define U 4
#define SEQLEN 64
#define NBLK 768

#define PINF(x) asm volatile("" : "+v"(x))

__device__ __forceinline__ float frcp(float x)  { return __builtin_amdgcn_rcpf(x); }
__device__ __forceinline__ float fexp2(float x) { return __builtin_amdgcn_exp2f(x); }

__device__ __forceinline__ float sigm(float x) {
    return frcp(1.0f + fexp2(-1.442695041f * x));
}
__device__ __forceinline__ float tanh_f(float x) {
    return 1.0f - 2.0f * frcp(fexp2(2.885390082f * x) + 1.0f);
}

// DPP quad_perm: xor1 = [1,0,3,2] = 0xB1, xor2 = [2,3,0,1] = 0x4E
template <int CTRL>
__device__ __forceinline__ float qp(float x) {
    return __int_as_float(
        __builtin_amdgcn_mov_dpp(__float_as_int(x), CTRL, 0xF, 0xF, true));
}

typedef union { float4 q[3]; float s[12]; } P12;

__device__ __forceinline__ void load12(const float* __restrict__ base, int tp, P12& d) {
    const float4* a = reinterpret_cast<const float4*>(base + (size_t)tp * 12);
    d.q[0] = a[0]; d.q[1] = a[1]; d.q[2] = a[2];
}

__device__ __forceinline__ float4 pairdot(const P12& bx, const P12& by,
                                          float v0, float v1, float v2,
                                          float v3, float v4, float v5) {
    float fx0 = bx.s[0] * v0, fy0 = by.s[0] * v0;
    float fx1 = bx.s[6] * v0, fy1 = by.s[6] * v0;
    fx0 = fmaf(bx.s[1],  v1, fx0); fy0 = fmaf(by.s[1],  v1, fy0);
    fx1 = fmaf(bx.s[7],  v1, fx1); fy1 = fmaf(by.s[7],  v1, fy1);
    fx0 = fmaf(bx.s[2],  v2, fx0); fy0 = fmaf(by.s[2],  v2, fy0);
    fx1 = fmaf(bx.s[8],  v2, fx1); fy1 = fmaf(by.s[8],  v2, fy1);
    fx0 = fmaf(bx.s[3],  v3, fx0); fy0 = fmaf(by.s[3],  v3, fy0);
    fx1 = fmaf(bx.s[9],  v3, fx1); fy1 = fmaf(by.s[9],  v3, fy1);
    fx0 = fmaf(bx.s[4],  v4, fx0); fy0 = fmaf(by.s[4],  v4, fy0);
    fx1 = fmaf(bx.s[10], v4, fx1); fy1 = fmaf(by.s[10], v4, fy1);
    fx0 = fmaf(bx.s[5],  v5, fx0); fy0 = fmaf(by.s[5],  v5, fy0);
    fx1 = fmaf(bx.s[11], v5, fx1); fy1 = fmaf(by.s[11], v5, fy1);
    float4 r; r.x = fx0; r.y = fy0; r.z = fx1; r.w = fy1;
    return r;
}

__global__ __launch_bounds__(256, 3) void fused_lstm_flow_kernel(
    const float* __restrict__ vel,
    const float* __restrict__ Wix, const float* __restrict__ Wih, const float* __restrict__ bi,
    const float* __restrict__ Wfx, const float* __restrict__ Wfh, const float* __restrict__ bf_,
    const float* __restrict__ Wox, const float* __restrict__ Woh, const float* __restrict__ bo,
    const float* __restrict__ Wgx, const float* __restrict__ Wgh, const float* __restrict__ bg,
    const float* __restrict__ lin, const float* __restrict__ bl,
    const float* __restrict__ h0,  const float* __restrict__ c0,
    const float* __restrict__ Lsx, const float* __restrict__ Lsy,
    float* __restrict__ out, int n)
{
    __shared__ float vels_s[8];

    const int tid = threadIdx.x;
    const int T   = gridDim.x * blockDim.x;
    const int tp0 = blockIdx.x * blockDim.x + tid;
    const int nt  = n >> 1;                 // pixel pairs
    const bool w0 = tid < 64;               // wave-uniform

    const bool cc0 = tp0 < nt;
    const bool cc1 = tp0 + T < nt;
    const bool cc2 = tp0 + 2 * T < nt;

    // ---- Wave 0: weight loads FIRST, pinned (cannot be sunk into the loop).
    float wix, bii, wfx, bff, wox, boo, wgx, bgg, li, blj;
    float wi0, wi1, wi2, wi3, wf0, wf1, wf2, wf3;
    float wo0, wo1, wo2, wo3, wg0, wg1, wg2, wg3;
    float h, c, x;

    if (w0 && tid < 24) {
        const int lane = tid;
        const int j  = lane >> 2;
        const int u  = lane & 3;
        const int r4 = lane * 4;        // row (4j+u) base into W*h weights (24x4)
        const int k1 = u ^ 1, k2 = u ^ 2, k3 = u ^ 3;

        wix = Wix[lane]; bii = bi[lane];
        wfx = Wfx[lane]; bff = bf_[lane];
        wox = Wox[lane]; boo = bo[lane];
        wgx = Wgx[lane]; bgg = bg[lane];
        li  = lin[lane]; blj = bl[j];

        // dot weights in butterfly arrival order: own(u), u^1, u^2, u^3
        wi0 = Wih[r4 + u];  wi1 = Wih[r4 + k1];
        wi2 = Wih[r4 + k2]; wi3 = Wih[r4 + k3];
        wf0 = Wfh[r4 + u];  wf1 = Wfh[r4 + k1];
        wf2 = Wfh[r4 + k2]; wf3 = Wfh[r4 + k3];
        wo0 = Woh[r4 + u];  wo1 = Woh[r4 + k1];
        wo2 = Woh[r4 + k2]; wo3 = Woh[r4 + k3];
        wg0 = Wgh[r4 + u];  wg1 = Wgh[r4 + k1];
        wg2 = Wgh[r4 + k2]; wg3 = Wgh[r4 + k3];

        h = h0[lane]; c = c0[lane]; x = vel[j];

        PINF(wix); PINF(bii); PINF(wfx); PINF(bff);
        PINF(wox); PINF(boo); PINF(wgx); PINF(bgg);
        PINF(li);  PINF(blj);
        PINF(wi0); PINF(wi1); PINF(wi2); PINF(wi3);
        PINF(wf0); PINF(wf1); PINF(wf2); PINF(wf3);
        PINF(wo0); PINF(wo1); PINF(wo2); PINF(wo3);
        PINF(wg0); PINF(wg1); PINF(wg2); PINF(wg3);
        PINF(h); PINF(c); PINF(x);
    }

    // Fence: chunk prefetch must not be hoisted above the weight loads
    // (weights issued first => their waitcnt leaves chunk loads in flight).
    asm volatile("" ::: "memory");

    // ---- Prefetch: chunk 0 everywhere; chunks 1,2 on waves 1-3 only
    //      (wave 0 keeps pressure low while weights are live).
    P12 b0x, b0y, b1x, b1y, b2x, b2y;
    if (cc0) { load12(Lsx, tp0, b0x); load12(Lsy, tp0, b0y); }
    if (!w0) {
        if (cc1) { load12(Lsx, tp0 + T,     b1x); load12(Lsy, tp0 + T,     b1y); }
        if (cc2) { load12(Lsx, tp0 + 2 * T, b2x); load12(Lsy, tp0 + 2 * T, b2y); }
    }

    // ---- Phase 1: LSTM on wave 0, lanes 0..23 (pinned weights) ----
    if (w0 && tid < 24) {
        float vels = 0.0f, o = 0.0f;

        for (int i = 0; i < SEQLEN; ++i) {
            if (i > 0) { vels += o; x = o; }

            const float hA = qp<0xB1>(h);
            const float hB = qp<0x4E>(h);
            const float hC = qp<0x4E>(hA);

            float pi = fmaf(wix, x, bii);
            pi = fmaf(wi0, h, pi); pi = fmaf(wi1, hA, pi);
            pi = fmaf(wi2, hB, pi); pi = fmaf(wi3, hC, pi);
            float pf = fmaf(wfx, x, bff);
            pf = fmaf(wf0, h, pf); pf = fmaf(wf1, hA, pf);
            pf = fmaf(wf2, hB, pf); pf = fmaf(wf3, hC, pf);
            float po = fmaf(wox, x, boo);
            po = fmaf(wo0, h, po); po = fmaf(wo1, hA, po);
            po = fmaf(wo2, hB, po); po = fmaf(wo3, hC, po);
            float pg = fmaf(wgx, x, bgg);
            pg = fmaf(wg0, h, pg); pg = fmaf(wg1, hA, pg);
            pg = fmaf(wg2, hB, pg); pg = fmaf(wg3, hC, pg);

            const float it = sigm(pi);
            const float ft = sigm(pf);
            const float ot = sigm(po);
            const float gt = sigm(pg);  // "cbar" is sigmoid in the source

            c = fmaf(ft, c, it * gt);
            h = ot * sigm(c);           // sigmoid, not tanh, as in source

            float s = li * h;
            s += qp<0xB1>(s);
            s += qp<0x4E>(s);
            o = tanh_f(s + blj);

            if (i == 0) vels = o;
        }

        if ((tid & 3) == 0) vels_s[tid >> 2] = vels;
    }

    __syncthreads();

    const float v0 = vels_s[0], v1 = vels_s[1], v2 = vels_s[2];
    const float v3 = vels_s[3], v4 = vels_s[4], v5 = vels_s[5];

    // Wave 0 catches up on chunks 1,2 (weights now dead; 96 regs fine).
    if (w0) {
        if (cc1) { load12(Lsx, tp0 + T,     b1x); load12(Lsy, tp0 + T,     b1y); }
        if (cc2) { load12(Lsx, tp0 + 2 * T, b2x); load12(Lsy, tp0 + 2 * T, b2y); }
    }

    // ---- Phase 2: 5 static chunks, max 3 live (144 regs), loads 2 ahead ----
    if (cc0) reinterpret_cast<float4*>(out)[tp0] =
        pairdot(b0x, b0y, v0, v1, v2, v3, v4, v5);        // c0 dies

    const bool cc3 = tp0 + 3 * T < nt;
    P12 b3x, b3y;
    if (cc3) { load12(Lsx, tp0 + 3 * T, b3x); load12(Lsy, tp0 + 3 * T, b3y); }

    if (cc1) reinterpret_cast<float4*>(out)[tp0 + T] =
        pairdot(b1x, b1y, v0, v1, v2, v3, v4, v5);        // c1 dies

    const bool cc4 = tp0 + 4 * T < nt;
    P12 b4x, b4y;
    if (cc4) { load12(Lsx, tp0 + 4 * T, b4x); load12(Lsy, tp0 + 4 * T, b4y); }

    if (cc2) reinterpret_cast<float4*>(out)[tp0 + 2 * T] =
        pairdot(b2x, b2y, v0, v1, v2, v3, v4, v5);        // c2 dies

    if (cc3) reinterpret_cast<float4*>(out)[tp0 + 3 * T] =
        pairdot(b3x, b3y, v0, v1, v2, v3, v4, v5);        // c3 dies

    if (cc4) reinterpret_cast<float4*>(out)[tp0 + 4 * T] =
        pairdot(b4x, b4y, v0, v1, v2, v3, v4, v5);

    // Remainder (tp0 + 5T.. ) — grid-stride
    for (int tp = tp0 + 5 * T; tp < nt; tp += T) {
        P12 cx, cy;
        load12(Lsx, tp, cx); load12(Lsy, tp, cy);
        reinterpret_cast<float4*>(out)[tp] =
            pairdot(cx, cy, v0, v1, v2, v3, v4, v5);
    }

    // Tail pixel if n is odd (not hit for 1920*1080)
    if ((n & 1) && blockIdx.x == 0 && tid == 0) {
        const int p = n - 1;
        float fx = 0.0f, fy = 0.0f;
        const float vv[6] = {v0, v1, v2, v3, v4, v5};
        for (int k = 0; k < 6; ++k) {
            fx = fmaf(Lsx[(size_t)p * 6 + k], vv[k], fx);
            fy = fmaf(Lsy[(size_t)p * 6 + k], vv[k], fy);
        }
        out[2 * p]     = fx;
        out[2 * p + 1] = fy;
    }
}

extern "C" void kernel_launch(void* const* d_in, const int* in_sizes, int n_in,
                              void* d_out, int out_size, void* d_ws, size_t ws_size,
                              hipStream_t stream)
{
    const float* vel  = (const float*)d_in[0];
    const float* Lsx  = (const float*)d_in[1];
    const float* Lsy  = (const float*)d_in[2];
    const float* Wix  = (const float*)d_in[3];
    const float* Wih  = (const float*)d_in[4];
    const float* bi   = (const float*)d_in[5];
    const float* Wfx  = (const float*)d_in[6];
    const float* Wfh  = (const float*)d_in[7];
    const float* bf_  = (const float*)d_in[8];
    const float* Wox  = (const float*)d_in[9];
    const float* Woh  = (const float*)d_in[10];
    const float* bo   = (const float*)d_in[11];
    const float* Wgx  = (const float*)d_in[12];
    const float* Wgh  = (const float*)d_in[13];
    const float* bg   = (const float*)d_in[14];
    const float* lin  = (const float*)d_in[15];
    const float* bl   = (const float*)d_in[16];
    const float* h0   = (const float*)d_in[17];
    const float* c0   = (const float*)d_in[18];

    const int n = in_sizes[1] / V;

    // 768 blocks = exactly 3/CU under launch_bounds(256,3): one residency
    // round, every block's LSTM fully covered by its 3-chunk prefetch drain.
    fused_lstm_flow_kernel<<<NBLK, 256, 0, stream>>>(
        vel, Wix, Wih, bi, Wfx, Wfh, bf_, Wox, Woh, bo, Wgx, Wgh, bg,
        lin, bl, h0, c0, Lsx, Lsy, (float*)d_out, n);
}